// Round 2
// baseline (198.611 us; speedup 1.0000x reference)
//
#include <hip/hip_runtime.h>
#include <math.h>

// ---------------------------------------------------------------------------
// TropicalMLP: h = logsumexp_j(x_j + w_ij) + b_i == log(sum_j e^x_j e^w_ij) + b_i
// Layer = fp32 GEMM on pre-exponentiated operands, log+bias fused downstream.
//
// GEMM: no LDS, no barriers. A (exp'd activations, row-major, K-contig) read
// via the SCALAR path (wave-uniform rows -> s_load); B^T (exp'd transposed
// weights, N-contig) as coalesced vector loads reused across 8 rows. Split-K=2
// gives 512 blocks (8 waves/CU). Combine fused into the LN / final kernels.
// LN: one wave per row, in-register bitonic sort (8 elem/lane, shfl_xor).
// ---------------------------------------------------------------------------

__global__ __launch_bounds__(256) void exp_kernel(const float* __restrict__ in,
                                                  float* __restrict__ out, int n4) {
    int i = blockIdx.x * 256 + threadIdx.x;
    if (i >= n4) return;
    float4 v = reinterpret_cast<const float4*>(in)[i];
    float4 r;
    r.x = expf(v.x); r.y = expf(v.y); r.z = expf(v.z); r.w = expf(v.w);
    reinterpret_cast<float4*>(out)[i] = r;
}

// Wt[k][n] = exp(W[n][k]).  W: Nr x Kc row-major.  32x32 LDS tile.
__global__ __launch_bounds__(256) void expT_w(const float* __restrict__ W,
                                              float* __restrict__ Wt,
                                              int Nr, int Kc) {
    __shared__ float t[32][33];
    const int tx = threadIdx.x & 31, ty = threadIdx.x >> 5;  // 32 x 8
    const int kb = blockIdx.x * 32, nb = blockIdx.y * 32;
#pragma unroll
    for (int i = 0; i < 4; ++i) {
        int n = nb + ty + i * 8;
        t[ty + i * 8][tx] = expf(W[n * Kc + kb + tx]);
    }
    __syncthreads();
#pragma unroll
    for (int i = 0; i < 4; ++i) {
        int k = kb + ty + i * 8;
        Wt[k * Nr + nb + tx] = t[tx][ty + i * 8];
    }
}

// P[z][m][n] = sum_{k in half z} A[m][k] * Bt[k][n]
// block = 4 waves stacked on m (32 rows); wave = 8 rows x 64 cols.
__global__ __launch_bounds__(256) void gemm_pk(const float* __restrict__ A,
                                               const float* __restrict__ Bt,
                                               float* __restrict__ P,
                                               int K, int N, int Khalf) {
    const int lane = threadIdx.x & 63;
    const int wid = __builtin_amdgcn_readfirstlane((int)(threadIdx.x >> 6));
    const int m0 = blockIdx.x * 32 + wid * 8;          // wave-uniform
    const int n = blockIdx.y * 64 + lane;
    const int kbase = blockIdx.z * Khalf;

    const float* a = A + m0 * K + kbase;               // uniform base -> s_load
    const float* b = Bt + kbase * N + n;

    float acc[8] = {0.f, 0.f, 0.f, 0.f, 0.f, 0.f, 0.f, 0.f};

    for (int k = 0; k < Khalf; k += 8) {
        float bv[8];
#pragma unroll
        for (int kk = 0; kk < 8; ++kk) bv[kk] = b[(k + kk) * N];
#pragma unroll
        for (int r = 0; r < 8; ++r) {
            const float* ar = a + r * K + k;
#pragma unroll
            for (int kk = 0; kk < 8; ++kk) acc[r] = fmaf(ar[kk], bv[kk], acc[r]);
        }
    }
    float* p = P + (size_t)blockIdx.z * 1024 * N;
#pragma unroll
    for (int r = 0; r < 8; ++r) p[(m0 + r) * N + n] = acc[r];
}

// Fused: h = log(P0+P1) + gb; tropical-LN (exact order stats, in-register
// bitonic sort, 1 wave per row, 8 elem/lane); relu; exp -> next layer's A.
__global__ __launch_bounds__(256) void ln_fused(const float* __restrict__ P,
                                                const float* __restrict__ gb,
                                                const float* __restrict__ lw,
                                                const float* __restrict__ lb,
                                                float* __restrict__ Eout) {
    const int lane = threadIdx.x & 63;
    const int wid = threadIdx.x >> 6;
    const int row = blockIdx.x * 4 + wid;
    const float* p0 = P + row * 512;
    const float* p1 = P + 1024 * 512 + row * 512;

    float h[8], v[8];
#pragma unroll
    for (int r = 0; r < 8; ++r) {
        int j = r * 64 + lane;
        h[r] = logf(p0[j] + p1[j]) + gb[j];
        v[r] = h[r];
    }
    // Bitonic sort of 512 values, element index e = r*64 + lane, ascending.
    for (int k = 2; k <= 512; k <<= 1) {
        for (int j = k >> 1; j >= 64; j >>= 1) {      // partner differs in r-bit
            int rj = j >> 6;
#pragma unroll
            for (int rl = 0; rl < 8; ++rl) {
                if (rl & rj) continue;
                int rh = rl | rj;
                int el = (rl << 6) | lane;
                bool up = ((el & k) == 0);
                float a = v[rl], c = v[rh];
                float lo = fminf(a, c), hi = fmaxf(a, c);
                v[rl] = up ? lo : hi;
                v[rh] = up ? hi : lo;
            }
        }
        for (int j = (k >> 1) > 32 ? 32 : (k >> 1); j > 0; j >>= 1) {  // lane-xor
#pragma unroll
            for (int r = 0; r < 8; ++r) {
                float p = __shfl_xor(v[r], j);
                int e = (r << 6) | lane;
                bool up = ((e & k) == 0);
                bool low = ((lane & j) == 0);
                v[r] = (up == low) ? fminf(v[r], p) : fmaxf(v[r], p);
            }
        }
    }
    float s127 = __shfl(v[1], 63);
    float s128 = __shfl(v[2], 0);
    float med  = __shfl(v[3], 63);
    float s383 = __shfl(v[5], 63);
    float s384 = __shfl(v[6], 0);
    float q25 = s127 + 0.75f * (s128 - s127);
    float q75 = s383 + 0.25f * (s384 - s383);
    float inv = 1.0f / fmaxf(q75 - q25, 1e-6f);
#pragma unroll
    for (int r = 0; r < 8; ++r) {
        int j = r * 64 + lane;
        float y = (h[r] - med) * inv * lw[j] + lb[j];
        y = fmaxf(y, 0.0f);
        Eout[row * 512 + j] = expf(y);
    }
}

// out[m][n] = log(P0+P1) + b3[n], 1024 x 256, float4.
__global__ __launch_bounds__(256) void final_combine(const float* __restrict__ P,
                                                     const float* __restrict__ b3,
                                                     float* __restrict__ out) {
    int i4 = blockIdx.x * 256 + threadIdx.x;           // 65536 float4s
    float4 a = reinterpret_cast<const float4*>(P)[i4];
    float4 b = reinterpret_cast<const float4*>(P + 1024 * 256)[i4];
    float4 bb = reinterpret_cast<const float4*>(b3)[i4 & 63];
    float4 o;
    o.x = logf(a.x + b.x) + bb.x;
    o.y = logf(a.y + b.y) + bb.y;
    o.z = logf(a.z + b.z) + bb.z;
    o.w = logf(a.w + b.w) + bb.w;
    reinterpret_cast<float4*>(out)[i4] = o;
}

extern "C" void kernel_launch(void* const* d_in, const int* in_sizes, int n_in,
                              void* d_out, int out_size, void* d_ws, size_t ws_size,
                              hipStream_t stream) {
    const float* x    = (const float*)d_in[0];
    const float* w1   = (const float*)d_in[1];
    const float* b1   = (const float*)d_in[2];
    const float* ln1w = (const float*)d_in[3];
    const float* ln1b = (const float*)d_in[4];
    const float* w2   = (const float*)d_in[5];
    const float* b2   = (const float*)d_in[6];
    const float* ln2w = (const float*)d_in[7];
    const float* ln2b = (const float*)d_in[8];
    const float* w3   = (const float*)d_in[9];
    const float* b3   = (const float*)d_in[10];
    float* out = (float*)d_out;

    float* ws = (float*)d_ws;
    float* E  = ws;                    // 1024*512           exp'd activations
    float* P  = E + 1024 * 512;        // 2*1024*512         split-K partials
    float* Wt = P + 2 * 1024 * 512;    // 512*512            exp'd W^T (reused)
    // total 7.0 MB

    // exp(x) -> E
    exp_kernel<<<512, 256, 0, stream>>>(x, E, 1024 * 512 / 4);

    // layer 1
    expT_w<<<dim3(16, 16), 256, 0, stream>>>(w1, Wt, 512, 512);
    gemm_pk<<<dim3(32, 8, 2), 256, 0, stream>>>(E, Wt, P, 512, 512, 256);
    ln_fused<<<256, 256, 0, stream>>>(P, b1, ln1w, ln1b, E);

    // layer 2
    expT_w<<<dim3(16, 16), 256, 0, stream>>>(w2, Wt, 512, 512);
    gemm_pk<<<dim3(32, 8, 2), 256, 0, stream>>>(E, Wt, P, 512, 512, 256);
    ln_fused<<<256, 256, 0, stream>>>(P, b2, ln2w, ln2b, E);

    // layer 3 (N=256) + combine straight to d_out
    expT_w<<<dim3(16, 8), 256, 0, stream>>>(w3, Wt, 256, 512);
    gemm_pk<<<dim3(32, 4, 2), 256, 0, stream>>>(E, Wt, P, 512, 256, 256);
    final_combine<<<256, 256, 0, stream>>>(P, b3, out);
}

// Round 3
// 130.302 us; speedup vs baseline: 1.5242x; 1.5242x over previous
//
#include <hip/hip_runtime.h>
#include <math.h>

// ---------------------------------------------------------------------------
// TropicalMLP: h_i = logsumexp_j(x_j + w_ij) + b_i == log(sum_j e^x_j e^w_ij) + b_i
// => layer = f16 MFMA GEMM on pre-exponentiated operands, log fused downstream.
// Per-row max subtracted before exp (cancels exactly in tropical-LN's
// (h - med)/iqr; added back in the final layer's epilogue) => f16-safe range.
// GEMM: 1 wave/block, 32x32 tile = 4x mfma_f32_16x16x32_f16, fragments loaded
// straight from global (A row-major [m][k], B as [n][k] = original w layout).
// LN: exact order stats via in-register bitonic sort, 1 wave/row, no barriers.
// ---------------------------------------------------------------------------

typedef _Float16 v8h __attribute__((ext_vector_type(8)));
typedef float v4f __attribute__((ext_vector_type(4)));

// exp of all three weight matrices -> f16, one kernel.
// w1: 512x512 (262144), w2: 512x512 (262144), w3: 256x512 (131072).
__global__ __launch_bounds__(256) void expW_kernel(const float* __restrict__ w1,
                                                   const float* __restrict__ w2,
                                                   const float* __restrict__ w3,
                                                   _Float16* __restrict__ Ew) {
    int e = (blockIdx.x * 256 + threadIdx.x) * 8;   // 320*256*8 = 655360 exactly
    const float* src;
    if (e < 262144) src = w1 + e;
    else if (e < 524288) src = w2 + (e - 262144);
    else src = w3 + (e - 524288);
    float4 a = *reinterpret_cast<const float4*>(src);
    float4 b = *reinterpret_cast<const float4*>(src + 4);
    v8h o;
    o[0] = (_Float16)__expf(a.x); o[1] = (_Float16)__expf(a.y);
    o[2] = (_Float16)__expf(a.z); o[3] = (_Float16)__expf(a.w);
    o[4] = (_Float16)__expf(b.x); o[5] = (_Float16)__expf(b.y);
    o[6] = (_Float16)__expf(b.z); o[7] = (_Float16)__expf(b.w);
    *reinterpret_cast<v8h*>(Ew + e) = o;
}

// E = exp(x) -> f16 (x ~ N(0,1): e^x <= ~150, no shift needed for layer 1).
__global__ __launch_bounds__(256) void expX_kernel(const float* __restrict__ in,
                                                   _Float16* __restrict__ out) {
    int e = (blockIdx.x * 256 + threadIdx.x) * 8;   // 256*256*8 = 524288 exactly
    float4 a = *reinterpret_cast<const float4*>(in + e);
    float4 b = *reinterpret_cast<const float4*>(in + e + 4);
    v8h o;
    o[0] = (_Float16)__expf(a.x); o[1] = (_Float16)__expf(a.y);
    o[2] = (_Float16)__expf(a.z); o[3] = (_Float16)__expf(a.w);
    o[4] = (_Float16)__expf(b.x); o[5] = (_Float16)__expf(b.y);
    o[6] = (_Float16)__expf(b.z); o[7] = (_Float16)__expf(b.w);
    *reinterpret_cast<v8h*>(out + e) = o;
}

// C[32m x 32n] = A[1024 x K] * B^T, B stored [n][k] (k-contig). 1 wave/block.
// A-frag: lane holds A[m0 + (lane&15)][k + (lane>>4)*8 + 0..7]  (16B dwordx4)
// B-frag: lane holds B[n0 + (lane&15)][k + (lane>>4)*8 + 0..7]
// C/D:    col = lane&15, row = (lane>>4)*4 + reg   (16x16x32 shape, verified)
// FINAL=0: store raw fp32 partials to P.  FINAL=1: out = log(acc)+c[row]+bias[col].
template <int FINAL>
__global__ __launch_bounds__(64) void gemm_mfma(const _Float16* __restrict__ A,
                                                const _Float16* __restrict__ B,
                                                float* __restrict__ P,
                                                const float* __restrict__ crow,
                                                const float* __restrict__ bias,
                                                int K, int N) {
    const int lane = threadIdx.x;
    const int m0 = blockIdx.x * 32, n0 = blockIdx.y * 32;
    const int r = lane & 15, q = lane >> 4;
    const _Float16* a0 = A + (m0 + r) * K + q * 8;
    const _Float16* a1 = a0 + 16 * K;
    const _Float16* b0 = B + (n0 + r) * K + q * 8;
    const _Float16* b1 = b0 + 16 * K;
    v4f acc00 = {}, acc01 = {}, acc10 = {}, acc11 = {};
#pragma unroll 4
    for (int k = 0; k < K; k += 32) {
        v8h A0 = *reinterpret_cast<const v8h*>(a0 + k);
        v8h A1 = *reinterpret_cast<const v8h*>(a1 + k);
        v8h B0 = *reinterpret_cast<const v8h*>(b0 + k);
        v8h B1 = *reinterpret_cast<const v8h*>(b1 + k);
        acc00 = __builtin_amdgcn_mfma_f32_16x16x32_f16(A0, B0, acc00, 0, 0, 0);
        acc01 = __builtin_amdgcn_mfma_f32_16x16x32_f16(A0, B1, acc01, 0, 0, 0);
        acc10 = __builtin_amdgcn_mfma_f32_16x16x32_f16(A1, B0, acc10, 0, 0, 0);
        acc11 = __builtin_amdgcn_mfma_f32_16x16x32_f16(A1, B1, acc11, 0, 0, 0);
    }
    v4f av[2][2] = {{acc00, acc01}, {acc10, acc11}};
#pragma unroll
    for (int i = 0; i < 2; ++i) {
        int rb = m0 + i * 16 + q * 4;
#pragma unroll
        for (int j = 0; j < 2; ++j) {
            int col = n0 + j * 16 + r;
            if (FINAL) {
                float bb = bias[col];
#pragma unroll
                for (int t = 0; t < 4; ++t)
                    P[(rb + t) * N + col] = __logf(av[i][j][t]) + crow[rb + t] + bb;
            } else {
#pragma unroll
                for (int t = 0; t < 4; ++t)
                    P[(rb + t) * N + col] = av[i][j][t];
            }
        }
    }
}

// Fused: h = log(P) + gb; tropical-LN (exact order stats via in-register
// bitonic sort, 1 wave/row, 8 elem/lane); relu; c = rowmax(y);
// E = f16(exp(y - c)); store c (used only by the final layer's epilogue;
// the uniform shift cancels exactly inside the next LN).
__global__ __launch_bounds__(256) void ln_fused(const float* __restrict__ P,
                                                const float* __restrict__ gb,
                                                const float* __restrict__ lw,
                                                const float* __restrict__ lb,
                                                _Float16* __restrict__ E,
                                                float* __restrict__ crow) {
    const int lane = threadIdx.x & 63;
    const int wid = threadIdx.x >> 6;
    const int row = blockIdx.x * 4 + wid;
    const float* p = P + row * 512;

    float h[8], v[8];
#pragma unroll
    for (int r = 0; r < 8; ++r) {
        int j = r * 64 + lane;
        h[r] = __logf(p[j]) + gb[j];
        v[r] = h[r];
    }
    // Bitonic sort of 512 values, element index e = r*64 + lane, ascending.
    for (int k = 2; k <= 512; k <<= 1) {
        for (int j = k >> 1; j >= 64; j >>= 1) {      // partner differs in r-bit
            int rj = j >> 6;
#pragma unroll
            for (int rl = 0; rl < 8; ++rl) {
                if (rl & rj) continue;
                int rh = rl | rj;
                int el = (rl << 6) | lane;
                bool up = ((el & k) == 0);
                float a = v[rl], c = v[rh];
                float lo = fminf(a, c), hi = fmaxf(a, c);
                v[rl] = up ? lo : hi;
                v[rh] = up ? hi : lo;
            }
        }
        for (int j = (k >> 1) > 32 ? 32 : (k >> 1); j > 0; j >>= 1) {  // lane-xor
#pragma unroll
            for (int r = 0; r < 8; ++r) {
                float pv = __shfl_xor(v[r], j);
                int e = (r << 6) | lane;
                bool up = ((e & k) == 0);
                bool low = ((lane & j) == 0);
                v[r] = (up == low) ? fminf(v[r], pv) : fmaxf(v[r], pv);
            }
        }
    }
    float s127 = __shfl(v[1], 63);
    float s128 = __shfl(v[2], 0);
    float med  = __shfl(v[3], 63);
    float s383 = __shfl(v[5], 63);
    float s384 = __shfl(v[6], 0);
    float q25 = s127 + 0.75f * (s128 - s127);
    float q75 = s383 + 0.25f * (s384 - s383);
    float inv = 1.0f / fmaxf(q75 - q25, 1e-6f);

    float y[8], cm = 0.0f;                      // y >= 0 after relu
#pragma unroll
    for (int r = 0; r < 8; ++r) {
        int j = r * 64 + lane;
        y[r] = fmaxf((h[r] - med) * inv * lw[j] + lb[j], 0.0f);
        cm = fmaxf(cm, y[r]);
    }
#pragma unroll
    for (int s = 32; s > 0; s >>= 1) cm = fmaxf(cm, __shfl_xor(cm, s));
#pragma unroll
    for (int r = 0; r < 8; ++r) {
        int j = r * 64 + lane;
        E[row * 512 + j] = (_Float16)__expf(y[r] - cm);
    }
    if (lane == 0) crow[row] = cm;
}

extern "C" void kernel_launch(void* const* d_in, const int* in_sizes, int n_in,
                              void* d_out, int out_size, void* d_ws, size_t ws_size,
                              hipStream_t stream) {
    const float* x    = (const float*)d_in[0];
    const float* w1   = (const float*)d_in[1];
    const float* b1   = (const float*)d_in[2];
    const float* ln1w = (const float*)d_in[3];
    const float* ln1b = (const float*)d_in[4];
    const float* w2   = (const float*)d_in[5];
    const float* b2   = (const float*)d_in[6];
    const float* ln2w = (const float*)d_in[7];
    const float* ln2b = (const float*)d_in[8];
    const float* w3   = (const float*)d_in[9];
    const float* b3   = (const float*)d_in[10];
    float* out = (float*)d_out;

    char* ws = (char*)d_ws;
    _Float16* E  = (_Float16*)ws;                    // 1024*512 f16 = 1 MB
    _Float16* Ew = (_Float16*)(ws + (1 << 20));      // 655360 f16  = 1.25 MB
    float*    P  = (float*)(ws + (5 << 19));         // 1024*512 f32 = 2 MB
    float*    c  = (float*)(ws + (9 << 19));         // 1024 f32
    _Float16* Ew1 = Ew;
    _Float16* Ew2 = Ew + 262144;
    _Float16* Ew3 = Ew + 524288;

    expW_kernel<<<320, 256, 0, stream>>>(w1, w2, w3, Ew);
    expX_kernel<<<256, 256, 0, stream>>>(x, E);

    gemm_mfma<0><<<dim3(32, 16), 64, 0, stream>>>(E, Ew1, P, nullptr, nullptr, 512, 512);
    ln_fused<<<256, 256, 0, stream>>>(P, b1, ln1w, ln1b, E, c);

    gemm_mfma<0><<<dim3(32, 16), 64, 0, stream>>>(E, Ew2, P, nullptr, nullptr, 512, 512);
    ln_fused<<<256, 256, 0, stream>>>(P, b2, ln2w, ln2b, E, c);

    gemm_mfma<1><<<dim3(32, 8), 64, 0, stream>>>(E, Ew3, out, c, b3, 512, 256);
}